// Round 7
// baseline (384.382 us; speedup 1.0000x reference)
//
#include <hip/hip_runtime.h>
#include <hip/hip_cooperative_groups.h>
#include <math.h>

#define LOG2E 1.44269504f

namespace cg = cooperative_groups;

typedef unsigned short us;
typedef __attribute__((ext_vector_type(8))) short bf16x8;
typedef __attribute__((ext_vector_type(4))) float f32x4;
typedef __attribute__((ext_vector_type(16))) float f32x16;

static __device__ __forceinline__ us f2bf(float f) {  // RNE
  union { float f; unsigned u; } v; v.f = f;
  unsigned r = v.u + 0x7fffu + ((v.u >> 16) & 1u);
  return (us)(r >> 16);
}

// ---------------------------------------------------------------------------
// mega_kernel: 512 blocks x 512 thr, cooperative. Block bid: b = bid&7
// (XCD-stable batch: all phases of this block touch batch b only, keeping
// its 4MB slices L2-local), u = bid>>3 = 64-row band.
//   Phase A (pm&1): transpose x[b][c][n] f32 -> xT[b][n][c] bf16 for the 4
//     channel-quarters of band u (reuses R3 prep's verified scheme, 512-thr
//     mapping); + weight repack strided 224/block.
//   Phase B (pm&2): conv band u: waves 0-3 q/k (K=768 im2col GEMM),
//     waves 4-7 v (1x1), outputs qT/kT[b][n][oc], vblk[b][n>>4][oc][n&15]
//     — identical math/layout to R3 conv_kernel.
//   Phase C (pm&4): attn for i-tile u — R3's best structure verbatim
//     (T15 reorder, swapped QK, cvt_pk P-writes, reg ping-pong prefetch,
//     lgkmcnt-only barrier drain).
// grid.sync() between phases only when pm==7 (cooperative path). Fallback:
// three classic launches pm=1,2,4.
// ---------------------------------------------------------------------------
__global__ __launch_bounds__(512, 4) void mega_kernel(
    const float* __restrict__ x, const float* __restrict__ wq,
    const float* __restrict__ wk, const float* __restrict__ wv,
    const float* __restrict__ bq, const float* __restrict__ bk,
    const float* __restrict__ bv, const float* __restrict__ gamma_p,
    float* __restrict__ out, us* __restrict__ xT, us* __restrict__ qT,
    us* __restrict__ kT, us* __restrict__ vblk, us* __restrict__ wqc,
    us* __restrict__ wkc, us* __restrict__ wvb, int pm) {
  __shared__ __align__(16) union {
    us lt[64 * 68];                       // phase A transpose tile (8.7KB)
    struct {
      us pb[2][64 * 72];                  // phase C P double-buffer
      float lpart[2][64];
    } c;                                   // (19KB)
  } sm;

  int tid = threadIdx.x, lane = tid & 63, w = tid >> 6;
  int l15 = lane & 15, quad = lane >> 4;
  int l31 = lane & 31, h32 = lane >> 5;
  int bid = blockIdx.x;
  int b = bid & 7, u = bid >> 3;

  // ========================= Phase A: prep =========================
  if (pm & 1) {
    int nb = u;
    int nl = tid & 63, ch = tid >> 6;  // ch 0..7
#pragma unroll 1
    for (int cb = 0; cb < 4; cb++) {
      const float* xb = x + (((size_t)(b * 256 + cb * 64)) << 12);
#pragma unroll
      for (int p = 0; p < 8; p++) {
        int c = p * 8 + ch;
        sm.lt[nl * 68 + c] = f2bf(xb[((size_t)c << 12) + (nb * 64 + nl)]);
      }
      __syncthreads();
      us* xTb = xT + (((size_t)b << 12) + nb * 64) * 256 + cb * 64;
      int cw = tid & 7, nr = tid >> 3;  // nr 0..63
      uint2 lo = *(const uint2*)&sm.lt[nr * 68 + cw * 8];
      uint2 hi = *(const uint2*)&sm.lt[nr * 68 + cw * 8 + 4];
      *(uint4*)&xTb[(size_t)nr * 256 + cw * 8] = make_uint4(lo.x, lo.y, hi.x, hi.y);
      __syncthreads();
    }
    // weight repack: 114688 = 512 blocks * 224
    if (tid < 224) {
      int idx = bid * 224 + tid;
      if (idx < 24576) {
        int oc = idx / 768, r = idx % 768, t = r >> 8, ic = r & 255;
        wqc[idx] = f2bf(wq[(oc * 256 + ic) * 3 + t] * LOG2E);
      } else if (idx < 49152) {
        int j = idx - 24576;
        int oc = j / 768, r = j % 768, t = r >> 8, ic = r & 255;
        wkc[j] = f2bf(wk[(oc * 256 + ic) * 3 + t]);
      } else {
        int j = idx - 49152;
        wvb[j] = f2bf(wv[j]);
      }
    }
  }
  if (pm == 7) cg::this_grid().sync();

  // ========================= Phase B: conv =========================
  if (pm & 2) {
    const us* xTb = xT + (((size_t)b << 12) * 256);
    int n0 = u * 64, y = u;
    if (w < 4) {
      // q/k conv (R3 conv first branch, w 0..3)
      bool isq = (w < 2);
      int m0 = (w & 1) * 16;
      const us* wc = isq ? wqc : wkc;
      f32x4 acc[4];
#pragma unroll
      for (int nt = 0; nt < 4; nt++) acc[nt] = (f32x4){0.f, 0.f, 0.f, 0.f};
#pragma unroll
      for (int t = 0; t < 3; t++) {
        bool killT = (!isq) && ((t == 0 && y == 0) || (t == 2 && y == 63));
        if (!killT) {
          int dn = isq ? (t - 1) : (t - 1) * 64;
#pragma unroll
          for (int k8 = 0; k8 < 8; k8++) {
            int kloc = t * 256 + k8 * 32 + quad * 8;
            bf16x8 af = *(const bf16x8*)(wc + (size_t)(m0 + l15) * 768 + kloc);
            int ic = k8 * 32 + quad * 8;
#pragma unroll
            for (int nt = 0; nt < 4; nt++) {
              int nl = nt * 16 + l15;
              int ns = n0 + nl + dn;
              ns = ns < 0 ? 0 : (ns > 4095 ? 4095 : ns);
              bf16x8 bf = *(const bf16x8*)(xTb + (size_t)ns * 256 + ic);
              if (isq && ((t == 0 && nl == 0) || (t == 2 && nl == 63)))
                bf = (bf16x8){0, 0, 0, 0, 0, 0, 0, 0};
              acc[nt] = __builtin_amdgcn_mfma_f32_16x16x32_bf16(af, bf, acc[nt], 0, 0, 0);
            }
          }
        }
      }
      const float* bias = isq ? bq : bk;
      float bsc = isq ? LOG2E : 1.0f;
      us* outp = (isq ? qT : kT) + (((size_t)b << 12) * 32);
      float b0 = bias[m0 + quad * 4 + 0] * bsc;
      float b1 = bias[m0 + quad * 4 + 1] * bsc;
      float b2 = bias[m0 + quad * 4 + 2] * bsc;
      float b3 = bias[m0 + quad * 4 + 3] * bsc;
#pragma unroll
      for (int nt = 0; nt < 4; nt++) {
        int n = n0 + nt * 16 + l15;
        unsigned lo = (unsigned)f2bf(acc[nt][0] + b0) | ((unsigned)f2bf(acc[nt][1] + b1) << 16);
        unsigned hi = (unsigned)f2bf(acc[nt][2] + b2) | ((unsigned)f2bf(acc[nt][3] + b3) << 16);
        *(uint2*)(outp + (size_t)n * 32 + m0 + quad * 4) = make_uint2(lo, hi);
      }
    } else {
      // v conv (R3 conv second branch, wv = w-4 in 0..3)
      int wv4 = w - 4;
      f32x4 acc[4][4];  // [ct][nt]
#pragma unroll
      for (int ct = 0; ct < 4; ct++)
#pragma unroll
        for (int nt = 0; nt < 4; nt++) acc[ct][nt] = (f32x4){0.f, 0.f, 0.f, 0.f};
#pragma unroll
      for (int kk = 0; kk < 8; kk++) {
        bf16x8 bfr[4];
#pragma unroll
        for (int nt = 0; nt < 4; nt++)
          bfr[nt] = *(const bf16x8*)(xTb + (size_t)(n0 + nt * 16 + l15) * 256 + kk * 32 + quad * 8);
#pragma unroll
        for (int ct = 0; ct < 4; ct++) {
          bf16x8 af = *(const bf16x8*)(wvb + (size_t)(wv4 * 64 + ct * 16 + l15) * 256 + kk * 32 + quad * 8);
#pragma unroll
          for (int nt = 0; nt < 4; nt++)
            acc[ct][nt] = __builtin_amdgcn_mfma_f32_16x16x32_bf16(af, bfr[nt], acc[ct][nt], 0, 0, 0);
        }
      }
      us* vb = vblk + ((size_t)b << 20);
#pragma unroll
      for (int ct = 0; ct < 4; ct++) {
#pragma unroll
        for (int r = 0; r < 4; r++) {
          int oc = wv4 * 64 + ct * 16 + quad * 4 + r;
          float bvv = bv[oc];
#pragma unroll
          for (int nt = 0; nt < 4; nt++) {
            vb[((size_t)(u * 4 + nt) * 256 + oc) * 16 + l15] = f2bf(acc[ct][nt][r] + bvv);
          }
        }
      }
    }
  }
  if (pm == 7) cg::this_grid().sync();

  // ========================= Phase C: attn (R3 verbatim) =========================
  if (pm & 4) {
    int tw = w & 3, jh = w >> 2;
    int i0 = u * 64;

    const us* qTb = qT + (((size_t)b << 12) * 32);
    const us* kTb = kT + (((size_t)b << 12) * 32);
    const us* vbb = vblk + ((size_t)b << 20);

    bf16x8 qf = *(const bf16x8*)(qTb + (size_t)(i0 + tw * 16 + l15) * 32 + quad * 8);

    const us* kbase = kTb + (size_t)(jh * 32 + l15) * 32 + quad * 8;   // +jt*2048
    const us* vbase = vbb + (size_t)(w * 32 + l31) * 16 + h32 * 8;     // +jt*16384
    int pwi = (tw * 16 + l15) * 72 + jh * 32 + quad * 4;
    int pri = l31 * 72 + h32 * 8;

    float lr = 0.f;
    f32x4 s0, s1;
    f32x16 o0, o1;
#pragma unroll
    for (int rg = 0; rg < 16; rg++) { o0[rg] = 0.f; o1[rg] = 0.f; }

    bf16x8 kS0a, kS0b, kS1a, kS1b;
    bf16x8 v0_0, v0_1, v0_2, v0_3;
    bf16x8 v1_0, v1_1, v1_2, v1_3;
    bf16x8 v2_0, v2_1, v2_2, v2_3;
    bf16x8 v3_0, v3_1, v3_2, v3_3;

#define PRE(JT, KN0, KN1, VN0, VN1, VN2, VN3)                                  \
  do {                                                                         \
    int jn = (JT) & 63;                                                        \
    const us* kp = kbase + (size_t)jn * 2048;                                  \
    const us* vp = vbase + (size_t)jn * 16384;                                 \
    KN0 = *(const bf16x8*)(kp);                                                \
    KN1 = *(const bf16x8*)(kp + 512);                                          \
    VN0 = *(const bf16x8*)(vp);                                                \
    VN1 = *(const bf16x8*)(vp + 4096);                                         \
    VN2 = *(const bf16x8*)(vp + 8192);                                         \
    VN3 = *(const bf16x8*)(vp + 12288);                                        \
  } while (0)

#define QKM(KC0, KC1)                                                          \
  do {                                                                         \
    s0 = __builtin_amdgcn_mfma_f32_16x16x32_bf16(KC0, qf, (f32x4){0.f, 0.f, 0.f, 0.f}, 0, 0, 0); \
    s1 = __builtin_amdgcn_mfma_f32_16x16x32_bf16(KC1, qf, (f32x4){0.f, 0.f, 0.f, 0.f}, 0, 0, 0); \
  } while (0)

#define PVM(BUFR, VP0, VP1, VP2, VP3)                                          \
  do {                                                                         \
    const us* pr = (const us*)sm.c.pb + (BUFR) * (64 * 72) + pri;              \
    __builtin_amdgcn_s_setprio(1);                                             \
    bf16x8 pf0, pf1;                                                           \
    pf0 = *(const bf16x8*)(pr + 0);                                            \
    pf1 = *(const bf16x8*)(pr + 32 * 72 + 0);                                  \
    o0 = __builtin_amdgcn_mfma_f32_32x32x16_bf16(VP0, pf0, o0, 0, 0, 0);       \
    o1 = __builtin_amdgcn_mfma_f32_32x32x16_bf16(VP0, pf1, o1, 0, 0, 0);       \
    pf0 = *(const bf16x8*)(pr + 16);                                           \
    pf1 = *(const bf16x8*)(pr + 32 * 72 + 16);                                 \
    o0 = __builtin_amdgcn_mfma_f32_32x32x16_bf16(VP1, pf0, o0, 0, 0, 0);       \
    o1 = __builtin_amdgcn_mfma_f32_32x32x16_bf16(VP1, pf1, o1, 0, 0, 0);       \
    pf0 = *(const bf16x8*)(pr + 32);                                           \
    pf1 = *(const bf16x8*)(pr + 32 * 72 + 32);                                 \
    o0 = __builtin_amdgcn_mfma_f32_32x32x16_bf16(VP2, pf0, o0, 0, 0, 0);       \
    o1 = __builtin_amdgcn_mfma_f32_32x32x16_bf16(VP2, pf1, o1, 0, 0, 0);       \
    pf0 = *(const bf16x8*)(pr + 48);                                           \
    pf1 = *(const bf16x8*)(pr + 32 * 72 + 48);                                 \
    o0 = __builtin_amdgcn_mfma_f32_32x32x16_bf16(VP3, pf0, o0, 0, 0, 0);       \
    o1 = __builtin_amdgcn_mfma_f32_32x32x16_bf16(VP3, pf1, o1, 0, 0, 0);       \
    __builtin_amdgcn_s_setprio(0);                                             \
  } while (0)

#define SMW(BUFW)                                                              \
  do {                                                                         \
    us* pw = (us*)sm.c.pb + (BUFW) * (64 * 72) + pwi;                          \
    {                                                                          \
      float p0 = __builtin_amdgcn_exp2f(s0[0]);                                \
      float p1 = __builtin_amdgcn_exp2f(s0[1]);                                \
      float p2 = __builtin_amdgcn_exp2f(s0[2]);                                \
      float p3 = __builtin_amdgcn_exp2f(s0[3]);                                \
      lr += (p0 + p1) + (p2 + p3);                                             \
      unsigned e0, e1;                                                         \
      asm("v_cvt_pk_bf16_f32 %0, %1, %2" : "=v"(e0) : "v"(p0), "v"(p1));       \
      asm("v_cvt_pk_bf16_f32 %0, %1, %2" : "=v"(e1) : "v"(p2), "v"(p3));       \
      *(uint2*)pw = make_uint2(e0, e1);                                        \
    }                                                                          \
    {                                                                          \
      float p0 = __builtin_amdgcn_exp2f(s1[0]);                                \
      float p1 = __builtin_amdgcn_exp2f(s1[1]);                                \
      float p2 = __builtin_amdgcn_exp2f(s1[2]);                                \
      float p3 = __builtin_amdgcn_exp2f(s1[3]);                                \
      lr += (p0 + p1) + (p2 + p3);                                             \
      unsigned e0, e1;                                                         \
      asm("v_cvt_pk_bf16_f32 %0, %1, %2" : "=v"(e0) : "v"(p0), "v"(p1));       \
      asm("v_cvt_pk_bf16_f32 %0, %1, %2" : "=v"(e1) : "v"(p2), "v"(p3));       \
      *(uint2*)(pw + 16) = make_uint2(e0, e1);                                 \
    }                                                                          \
  } while (0)

#define BAR                                                                    \
  do {                                                                         \
    asm volatile("s_waitcnt lgkmcnt(0)" ::: "memory");                         \
    __builtin_amdgcn_s_barrier();                                              \
    __builtin_amdgcn_sched_barrier(0);                                         \
  } while (0)

    PRE(0, kS0a, kS0b, v0_0, v0_1, v0_2, v0_3);
    PRE(1, kS1a, kS1b, v1_0, v1_1, v1_2, v1_3);
    QKM(kS0a, kS0b);
    SMW(0);
    BAR;
    PRE(2, kS0a, kS0b, v2_0, v2_1, v2_2, v2_3);
    QKM(kS1a, kS1b);
    PVM(0, v0_0, v0_1, v0_2, v0_3);
    SMW(1);
    BAR;
    PRE(3, kS1a, kS1b, v3_0, v3_1, v3_2, v3_3);
    QKM(kS0a, kS0b);
    PVM(1, v1_0, v1_1, v1_2, v1_3);
    SMW(0);
    BAR;
    PRE(4, kS0a, kS0b, v0_0, v0_1, v0_2, v0_3);
    QKM(kS1a, kS1b);
    PVM(0, v2_0, v2_1, v2_2, v2_3);
    SMW(1);
    BAR;

    for (int n4 = 1; n4 < 16; n4++) {
      int n = n4 * 4;
      PRE(n + 1, kS1a, kS1b, v1_0, v1_1, v1_2, v1_3);
      QKM(kS0a, kS0b);
      PVM(1, v3_0, v3_1, v3_2, v3_3);
      SMW(0);
      BAR;
      PRE(n + 2, kS0a, kS0b, v2_0, v2_1, v2_2, v2_3);
      QKM(kS1a, kS1b);
      PVM(0, v0_0, v0_1, v0_2, v0_3);
      SMW(1);
      BAR;
      PRE(n + 3, kS1a, kS1b, v3_0, v3_1, v3_2, v3_3);
      QKM(kS0a, kS0b);
      PVM(1, v1_0, v1_1, v1_2, v1_3);
      SMW(0);
      BAR;
      PRE(n + 4, kS0a, kS0b, v0_0, v0_1, v0_2, v0_3);
      QKM(kS1a, kS1b);
      PVM(0, v2_0, v2_1, v2_2, v2_3);
      SMW(1);
      BAR;
    }
    PVM(1, v3_0, v3_1, v3_2, v3_3);

#undef PRE
#undef QKM
#undef PVM
#undef SMW
#undef BAR

    float lt2 = lr;
    lt2 += __shfl_xor(lt2, 16);
    lt2 += __shfl_xor(lt2, 32);
    if (quad == 0) sm.c.lpart[jh][tw * 16 + l15] = lt2;
    __syncthreads();
    float g = gamma_p[0];
    const float* xb = x + ((size_t)b << 20);
    float* ob = out + ((size_t)b << 20);
    float gl[2];
#pragma unroll
    for (int it = 0; it < 2; it++) {
      int i = it * 32 + l31;
      gl[it] = g / (sm.c.lpart[0][i] + sm.c.lpart[1][i]);
    }
#pragma unroll
    for (int it = 0; it < 2; it++) {
      int i = i0 + it * 32 + l31;
      const f32x16& o = (it == 0) ? o0 : o1;
#pragma unroll
      for (int rg = 0; rg < 16; rg++) {
        int c = w * 32 + ((rg & 3) + 8 * (rg >> 2) + 4 * h32);
        size_t idx = ((size_t)c << 12) + i;
        ob[idx] = o[rg] * gl[it] + xb[idx];
      }
    }
  }
}

// ---------------------------------------------------------------------------
extern "C" void kernel_launch(void* const* d_in, const int* in_sizes, int n_in,
                              void* d_out, int out_size, void* d_ws, size_t ws_size,
                              hipStream_t stream) {
  const float* x = (const float*)d_in[0];
  const float* wq = (const float*)d_in[1];
  const float* bq = (const float*)d_in[2];
  const float* wk = (const float*)d_in[3];
  const float* bk = (const float*)d_in[4];
  const float* wv = (const float*)d_in[5];
  const float* bv = (const float*)d_in[6];
  const float* gamma = (const float*)d_in[7];
  float* out = (float*)d_out;

  us* xT = (us*)d_ws;                 // 8,388,608
  us* qT = xT + (size_t)8388608;      // 1,048,576
  us* kT = qT + (size_t)1048576;      // 1,048,576
  us* vblk = kT + (size_t)1048576;    // 8,388,608
  us* wqc = vblk + (size_t)8388608;   // 24,576
  us* wkc = wqc + (size_t)24576;      // 24,576
  us* wvb = wkc + (size_t)24576;      // 65,536

  int pm_all = 7;
  void* args[] = {(void*)&x,    (void*)&wq,   (void*)&wk,   (void*)&wv,
                  (void*)&bq,   (void*)&bk,   (void*)&bv,   (void*)&gamma,
                  (void*)&out,  (void*)&xT,   (void*)&qT,   (void*)&kT,
                  (void*)&vblk, (void*)&wqc,  (void*)&wkc,  (void*)&wvb,
                  (void*)&pm_all};
  hipError_t e = hipLaunchCooperativeKernel((const void*)mega_kernel, dim3(512),
                                            dim3(512), args, 0, stream);
  if (e != hipSuccess) {
    // fallback: three classic launches, phase-masked (no grid.sync executed)
    mega_kernel<<<512, 512, 0, stream>>>(x, wq, wk, wv, bq, bk, bv, gamma, out,
                                         xT, qT, kT, vblk, wqc, wkc, wvb, 1);
    mega_kernel<<<512, 512, 0, stream>>>(x, wq, wk, wv, bq, bk, bv, gamma, out,
                                         xT, qT, kT, vblk, wqc, wkc, wvb, 2);
    mega_kernel<<<512, 512, 0, stream>>>(x, wq, wk, wv, bq, bk, bv, gamma, out,
                                         xT, qT, kT, vblk, wqc, wkc, wvb, 4);
  }
}

// Round 8
// 248.913 us; speedup vs baseline: 1.5442x; 1.5442x over previous
//
#include <hip/hip_runtime.h>
#include <math.h>

#define LOG2E 1.44269504f

typedef unsigned short us;
typedef __attribute__((ext_vector_type(8))) short bf16x8;
typedef __attribute__((ext_vector_type(4))) float f32x4;
typedef __attribute__((ext_vector_type(16))) float f32x16;

static __device__ __forceinline__ us f2bf(float f) {  // RNE
  union { float f; unsigned u; } v; v.f = f;
  unsigned r = v.u + 0x7fffu + ((v.u >> 16) & 1u);
  return (us)(r >> 16);
}

// ---------------------------------------------------------------------------
// prep_kernel (R3 measured-best): blocks 0..2047 transpose x f32 -> xT bf16;
// blocks 2048..2495 weight repack.
// ---------------------------------------------------------------------------
__global__ __launch_bounds__(256) void prep_kernel(
    const float* __restrict__ x, const float* __restrict__ wq,
    const float* __restrict__ wk, const float* __restrict__ wv,
    us* __restrict__ xT, us* __restrict__ wqc, us* __restrict__ wkc,
    us* __restrict__ wvb) {
  __shared__ __align__(16) us lt[64 * 68];
  int bid = blockIdx.x;
  int tid = threadIdx.x;
  if (bid < 2048) {
    int b = bid >> 8, cb = (bid >> 6) & 3, nb = bid & 63;
    const float* xb = x + (((size_t)(b * 256 + cb * 64)) << 12);
    int nl = tid & 63, ch = tid >> 6;
#pragma unroll
    for (int p = 0; p < 16; p++) {
      int c = p * 4 + ch;
      lt[nl * 68 + c] = f2bf(xb[((size_t)c << 12) + (nb * 64 + nl)]);
    }
    __syncthreads();
    us* xTb = xT + (((size_t)b << 12) + nb * 64) * 256 + cb * 64;
    int cw = tid & 7, nr0 = tid >> 3;
#pragma unroll
    for (int p2 = 0; p2 < 2; p2++) {
      int nr = p2 * 32 + nr0;
      uint2 lo = *(const uint2*)&lt[nr * 68 + cw * 8];
      uint2 hi = *(const uint2*)&lt[nr * 68 + cw * 8 + 4];
      *(uint4*)&xTb[(size_t)nr * 256 + cw * 8] = make_uint4(lo.x, lo.y, hi.x, hi.y);
    }
  } else {
    int idx = (bid - 2048) * 256 + tid;
    if (idx < 24576) {
      int oc = idx / 768, r = idx % 768, t = r >> 8, ic = r & 255;
      wqc[idx] = f2bf(wq[(oc * 256 + ic) * 3 + t] * LOG2E);
    } else if (idx < 49152) {
      int j = idx - 24576;
      int oc = j / 768, r = j % 768, t = r >> 8, ic = r & 255;
      wkc[j] = f2bf(wk[(oc * 256 + ic) * 3 + t]);
    } else if (idx < 114688) {
      int j = idx - 49152;
      wvb[j] = f2bf(wv[j]);
    }
  }
}

// ---------------------------------------------------------------------------
// conv_kernel (R3 measured-best): blocks 0..511 q/k convs; 512..1023 v conv.
// ---------------------------------------------------------------------------
__global__ __launch_bounds__(256) void conv_kernel(
    const us* __restrict__ xT, const us* __restrict__ wqc,
    const us* __restrict__ wkc, const float* __restrict__ bq,
    const float* __restrict__ bk, const us* __restrict__ wvb,
    const float* __restrict__ bv, us* __restrict__ qT, us* __restrict__ kT,
    us* __restrict__ vblk) {
  int tid = threadIdx.x, lane = tid & 63, w = tid >> 6;
  int l15 = lane & 15, quad = lane >> 4;
  if (blockIdx.x < 512) {
    int bid = blockIdx.x;
    int b = bid & 7, rt = bid >> 3;
    int n0 = rt * 64, y = rt;
    bool isq = (w < 2);
    int m0 = (w & 1) * 16;
    const us* wc = isq ? wqc : wkc;
    const us* xTb = xT + (((size_t)b << 12) * 256);
    f32x4 acc[4];
#pragma unroll
    for (int nt = 0; nt < 4; nt++) acc[nt] = (f32x4){0.f, 0.f, 0.f, 0.f};
#pragma unroll
    for (int t = 0; t < 3; t++) {
      bool killT = (!isq) && ((t == 0 && y == 0) || (t == 2 && y == 63));
      if (!killT) {
        int dn = isq ? (t - 1) : (t - 1) * 64;
#pragma unroll
        for (int k8 = 0; k8 < 8; k8++) {
          int kloc = t * 256 + k8 * 32 + quad * 8;
          bf16x8 af = *(const bf16x8*)(wc + (size_t)(m0 + l15) * 768 + kloc);
          int ic = k8 * 32 + quad * 8;
#pragma unroll
          for (int nt = 0; nt < 4; nt++) {
            int nl = nt * 16 + l15;
            int ns = n0 + nl + dn;
            ns = ns < 0 ? 0 : (ns > 4095 ? 4095 : ns);
            bf16x8 bf = *(const bf16x8*)(xTb + (size_t)ns * 256 + ic);
            if (isq && ((t == 0 && nl == 0) || (t == 2 && nl == 63)))
              bf = (bf16x8){0, 0, 0, 0, 0, 0, 0, 0};
            acc[nt] = __builtin_amdgcn_mfma_f32_16x16x32_bf16(af, bf, acc[nt], 0, 0, 0);
          }
        }
      }
    }
    const float* bias = isq ? bq : bk;
    float bsc = isq ? LOG2E : 1.0f;
    us* outp = (isq ? qT : kT) + (((size_t)b << 12) * 32);
    float b0 = bias[m0 + quad * 4 + 0] * bsc;
    float b1 = bias[m0 + quad * 4 + 1] * bsc;
    float b2 = bias[m0 + quad * 4 + 2] * bsc;
    float b3 = bias[m0 + quad * 4 + 3] * bsc;
#pragma unroll
    for (int nt = 0; nt < 4; nt++) {
      int n = n0 + nt * 16 + l15;
      unsigned lo = (unsigned)f2bf(acc[nt][0] + b0) | ((unsigned)f2bf(acc[nt][1] + b1) << 16);
      unsigned hi = (unsigned)f2bf(acc[nt][2] + b2) | ((unsigned)f2bf(acc[nt][3] + b3) << 16);
      *(uint2*)(outp + (size_t)n * 32 + m0 + quad * 4) = make_uint2(lo, hi);
    }
  } else {
    int bid = blockIdx.x - 512;
    int b = bid & 7, nt0 = bid >> 3;
    int n0 = nt0 * 64;
    const us* xTb = xT + (((size_t)b << 12) * 256);
    f32x4 acc[4][4];  // [ct][nt]
#pragma unroll
    for (int ct = 0; ct < 4; ct++)
#pragma unroll
      for (int nt = 0; nt < 4; nt++) acc[ct][nt] = (f32x4){0.f, 0.f, 0.f, 0.f};
#pragma unroll
    for (int kk = 0; kk < 8; kk++) {
      bf16x8 bfr[4];
#pragma unroll
      for (int nt = 0; nt < 4; nt++)
        bfr[nt] = *(const bf16x8*)(xTb + (size_t)(n0 + nt * 16 + l15) * 256 + kk * 32 + quad * 8);
#pragma unroll
      for (int ct = 0; ct < 4; ct++) {
        bf16x8 af = *(const bf16x8*)(wvb + (size_t)(w * 64 + ct * 16 + l15) * 256 + kk * 32 + quad * 8);
#pragma unroll
        for (int nt = 0; nt < 4; nt++)
          acc[ct][nt] = __builtin_amdgcn_mfma_f32_16x16x32_bf16(af, bfr[nt], acc[ct][nt], 0, 0, 0);
      }
    }
    us* vb = vblk + ((size_t)b << 20);
#pragma unroll
    for (int ct = 0; ct < 4; ct++) {
#pragma unroll
      for (int r = 0; r < 4; r++) {
        int oc = w * 64 + ct * 16 + quad * 4 + r;
        float bvv = bv[oc];
#pragma unroll
        for (int nt = 0; nt < 4; nt++) {
          vb[((size_t)((n0 >> 4) + nt) * 256 + oc) * 16 + l15] = f2bf(acc[ct][nt][r] + bvv);
        }
      }
    }
  }
}

// ---------------------------------------------------------------------------
// Flash attention, 32-row i-tiles for occupancy: grid 1024 (= 8b XCD-stable
// x 128 i-tiles) -> 4 blocks/CU x 8 waves = 32 waves/CU (was 16). The serial
// QK->softmax->barrier->PV chain (R6 falsified barrier-count theory; chain
// is latency) is hidden by 2x block-level TLP instead of shortened.
// Per wave: iw=w&1 (i half), jq=w>>1 (j quarter): 1 QK mfma(k,q) -> 4 exp2,
// 2 cvt_pk, one b64 P-write; PV: c=w*32, 4x mfma_32x32x16 into ONE f32x16.
// VGPR budget ~60 (o16+V16+K8+q4+s4+temps) -> __launch_bounds__(512,8)
// pins 8 waves/SIMD. V single-set (T15 dropped: 2nd V set = +16 VGPR would
// halve occupancy). K ping-pong one iter ahead. lgkmcnt-only barrier drain
// keeps K/V global loads in flight across the barrier. Same 2-buffer
// invariant as R3: BAR(n+1)'s lgkmcnt(0) drains PV(n) reads before any wave
// reaches SMW(n+2) on that buffer.
// ---------------------------------------------------------------------------
__global__ __launch_bounds__(512, 8) void attn_kernel(
    const float* __restrict__ x, const us* __restrict__ qT,
    const us* __restrict__ kT, const us* __restrict__ vblk,
    const float* __restrict__ gamma_p, float* __restrict__ out) {
  __shared__ __align__(16) us pb[2][32 * 72];  // [i 0..31][j 0..63], stride 72
  __shared__ float lpart[4][32];

  int tid = threadIdx.x, lane = tid & 63, w = tid >> 6;
  int l15 = lane & 15, quad = lane >> 4;
  int l31 = lane & 31, h32 = lane >> 5;
  int iw = w & 1, jq = w >> 1;  // i half (16 rows), j quarter (16 cols)

  int bid = blockIdx.x;
  int b = bid & 7, i0 = (bid >> 3) * 32;

  const us* qTb = qT + (((size_t)b << 12) * 32);
  const us* kTb = kT + (((size_t)b << 12) * 32);
  const us* vbb = vblk + ((size_t)b << 20);

  bf16x8 qf = *(const bf16x8*)(qTb + (size_t)(i0 + iw * 16 + l15) * 32 + quad * 8);

  // per-thread invariant addresses (us units)
  const us* kbase = kTb + (size_t)(jq * 16 + l15) * 32 + quad * 8;  // +jt*2048
  const us* vbase = vbb + (size_t)(w * 32 + l31) * 16 + h32 * 8;    // +jt*16384
  int pwi = (iw * 16 + l15) * 72 + jq * 16 + quad * 4;  // P write [i][j]
  int pri = l31 * 72 + h32 * 8;                         // PV read base

  float lr = 0.f;
  f32x4 s;
  f32x16 o;  // c-tile = w*32, i = l31
#pragma unroll
  for (int rg = 0; rg < 16; rg++) o[rg] = 0.f;

  bf16x8 kX, kY;               // K ping-pong (1 frag each)
  bf16x8 vf0, vf1, vf2, vf3;   // V single set

#define PREK(N, KD)                                                            \
  do { KD = *(const bf16x8*)(kbase + (size_t)((N) & 63) * 2048); } while (0)

#define PREV(N)                                                                \
  do {                                                                         \
    const us* vp = vbase + (size_t)((N) & 63) * 16384;                         \
    vf0 = *(const bf16x8*)(vp);                                                \
    vf1 = *(const bf16x8*)(vp + 4096);                                         \
    vf2 = *(const bf16x8*)(vp + 8192);                                         \
    vf3 = *(const bf16x8*)(vp + 12288);                                        \
  } while (0)

#define STEP(N, KC, KN, BUF)                                                   \
  do {                                                                         \
    __builtin_amdgcn_s_setprio(1);                                             \
    s = __builtin_amdgcn_mfma_f32_16x16x32_bf16(KC, qf, (f32x4){0.f, 0.f, 0.f, 0.f}, 0, 0, 0); \
    __builtin_amdgcn_s_setprio(0);                                             \
    PREV(N);                                                                   \
    PREK((N) + 1, KN);                                                         \
    {                                                                          \
      float p0 = __builtin_amdgcn_exp2f(s[0]);                                 \
      float p1 = __builtin_amdgcn_exp2f(s[1]);                                 \
      float p2 = __builtin_amdgcn_exp2f(s[2]);                                 \
      float p3 = __builtin_amdgcn_exp2f(s[3]);                                 \
      lr += (p0 + p1) + (p2 + p3);                                             \
      unsigned e0, e1;                                                         \
      asm("v_cvt_pk_bf16_f32 %0, %1, %2" : "=v"(e0) : "v"(p0), "v"(p1));       \
      asm("v_cvt_pk_bf16_f32 %0, %1, %2" : "=v"(e1) : "v"(p2), "v"(p3));       \
      *(uint2*)((us*)pb + (BUF) * (32 * 72) + pwi) = make_uint2(e0, e1);       \
    }                                                                          \
    asm volatile("s_waitcnt lgkmcnt(0)" ::: "memory");                         \
    __builtin_amdgcn_s_barrier();                                              \
    __builtin_amdgcn_sched_barrier(0);                                         \
    {                                                                          \
      const us* pr = (const us*)pb + (BUF) * (32 * 72) + pri;                  \
      __builtin_amdgcn_s_setprio(1);                                           \
      bf16x8 pf;                                                               \
      pf = *(const bf16x8*)(pr + 0);                                           \
      o = __builtin_amdgcn_mfma_f32_32x32x16_bf16(vf0, pf, o, 0, 0, 0);        \
      pf = *(const bf16x8*)(pr + 16);                                          \
      o = __builtin_amdgcn_mfma_f32_32x32x16_bf16(vf1, pf, o, 0, 0, 0);        \
      pf = *(const bf16x8*)(pr + 32);                                          \
      o = __builtin_amdgcn_mfma_f32_32x32x16_bf16(vf2, pf, o, 0, 0, 0);        \
      pf = *(const bf16x8*)(pr + 48);                                          \
      o = __builtin_amdgcn_mfma_f32_32x32x16_bf16(vf3, pf, o, 0, 0, 0);        \
      __builtin_amdgcn_s_setprio(0);                                           \
    }                                                                          \
  } while (0)

  PREK(0, kX);
  for (int n2 = 0; n2 < 32; n2++) {
    STEP(2 * n2, kX, kY, 0);
    STEP(2 * n2 + 1, kY, kX, 1);
  }
#undef PREK
#undef PREV
#undef STEP

  // ---- final l: lane (l15,quad) holds partial over its (jq, quad) j-subset
  //      at i=iw*16+l15; reduce over quad (lane^16, ^32), combine 4 jq
  //      quarters via LDS ----
  float lt = lr;
  lt += __shfl_xor(lt, 16);
  lt += __shfl_xor(lt, 32);
  if (quad == 0) lpart[jq][iw * 16 + l15] = lt;
  __syncthreads();
  float g = gamma_p[0];
  const float* xb = x + ((size_t)b << 20);
  float* ob = out + ((size_t)b << 20);
  float gl = g / (lpart[0][l31] + lpart[1][l31] + lpart[2][l31] + lpart[3][l31]);
  int i = i0 + l31;
#pragma unroll
  for (int rg = 0; rg < 16; rg++) {
    int c = w * 32 + ((rg & 3) + 8 * (rg >> 2) + 4 * h32);
    size_t idx = ((size_t)c << 12) + i;
    ob[idx] = o[rg] * gl + xb[idx];
  }
}

// ---------------------------------------------------------------------------
extern "C" void kernel_launch(void* const* d_in, const int* in_sizes, int n_in,
                              void* d_out, int out_size, void* d_ws, size_t ws_size,
                              hipStream_t stream) {
  const float* x = (const float*)d_in[0];
  const float* wq = (const float*)d_in[1];
  const float* bq = (const float*)d_in[2];
  const float* wk = (const float*)d_in[3];
  const float* bk = (const float*)d_in[4];
  const float* wv = (const float*)d_in[5];
  const float* bv = (const float*)d_in[6];
  const float* gamma = (const float*)d_in[7];
  float* out = (float*)d_out;

  us* xT = (us*)d_ws;                 // 8,388,608
  us* qT = xT + (size_t)8388608;      // 1,048,576
  us* kT = qT + (size_t)1048576;      // 1,048,576
  us* vblk = kT + (size_t)1048576;    // 8,388,608
  us* wqc = vblk + (size_t)8388608;   // 24,576
  us* wkc = wqc + (size_t)24576;      // 24,576
  us* wvb = wkc + (size_t)24576;      // 65,536

  prep_kernel<<<2496, 256, 0, stream>>>(x, wq, wk, wv, xT, wqc, wkc, wvb);
  conv_kernel<<<1024, 256, 0, stream>>>(xT, wqc, wkc, bq, bk, wvb, bv, qT, kT, vblk);
  attn_kernel<<<1024, 512, 0, stream>>>(x, qT, kT, vblk, gamma, out);
}

// Round 9
// 238.944 us; speedup vs baseline: 1.6087x; 1.0417x over previous
//
#include <hip/hip_runtime.h>
#include <math.h>

#define LOG2E 1.44269504f

typedef unsigned short us;
typedef __attribute__((ext_vector_type(8))) short bf16x8;
typedef __attribute__((ext_vector_type(4))) float f32x4;
typedef __attribute__((ext_vector_type(16))) float f32x16;

static __device__ __forceinline__ us f2bf(float f) {  // RNE
  union { float f; unsigned u; } v; v.f = f;
  unsigned r = v.u + 0x7fffu + ((v.u >> 16) & 1u);
  return (us)(r >> 16);
}

// ---------------------------------------------------------------------------
// prep_kernel (R3 measured-best): blocks 0..2047 transpose x f32 -> xT bf16;
// blocks 2048..2495 weight repack.
// ---------------------------------------------------------------------------
__global__ __launch_bounds__(256) void prep_kernel(
    const float* __restrict__ x, const float* __restrict__ wq,
    const float* __restrict__ wk, const float* __restrict__ wv,
    us* __restrict__ xT, us* __restrict__ wqc, us* __restrict__ wkc,
    us* __restrict__ wvb) {
  __shared__ __align__(16) us lt[64 * 68];
  int bid = blockIdx.x;
  int tid = threadIdx.x;
  if (bid < 2048) {
    int b = bid >> 8, cb = (bid >> 6) & 3, nb = bid & 63;
    const float* xb = x + (((size_t)(b * 256 + cb * 64)) << 12);
    int nl = tid & 63, ch = tid >> 6;
#pragma unroll
    for (int p = 0; p < 16; p++) {
      int c = p * 4 + ch;
      lt[nl * 68 + c] = f2bf(xb[((size_t)c << 12) + (nb * 64 + nl)]);
    }
    __syncthreads();
    us* xTb = xT + (((size_t)b << 12) + nb * 64) * 256 + cb * 64;
    int cw = tid & 7, nr0 = tid >> 3;
#pragma unroll
    for (int p2 = 0; p2 < 2; p2++) {
      int nr = p2 * 32 + nr0;
      uint2 lo = *(const uint2*)&lt[nr * 68 + cw * 8];
      uint2 hi = *(const uint2*)&lt[nr * 68 + cw * 8 + 4];
      *(uint4*)&xTb[(size_t)nr * 256 + cw * 8] = make_uint4(lo.x, lo.y, hi.x, hi.y);
    }
  } else {
    int idx = (bid - 2048) * 256 + tid;
    if (idx < 24576) {
      int oc = idx / 768, r = idx % 768, t = r >> 8, ic = r & 255;
      wqc[idx] = f2bf(wq[(oc * 256 + ic) * 3 + t] * LOG2E);
    } else if (idx < 49152) {
      int j = idx - 24576;
      int oc = j / 768, r = j % 768, t = r >> 8, ic = r & 255;
      wkc[j] = f2bf(wk[(oc * 256 + ic) * 3 + t]);
    } else if (idx < 114688) {
      int j = idx - 49152;
      wvb[j] = f2bf(wv[j]);
    }
  }
}

// ---------------------------------------------------------------------------
// conv_kernel (R3 measured-best): blocks 0..511 q/k convs; 512..1023 v conv.
// ---------------------------------------------------------------------------
__global__ __launch_bounds__(256) void conv_kernel(
    const us* __restrict__ xT, const us* __restrict__ wqc,
    const us* __restrict__ wkc, const float* __restrict__ bq,
    const float* __restrict__ bk, const us* __restrict__ wvb,
    const float* __restrict__ bv, us* __restrict__ qT, us* __restrict__ kT,
    us* __restrict__ vblk) {
  int tid = threadIdx.x, lane = tid & 63, w = tid >> 6;
  int l15 = lane & 15, quad = lane >> 4;
  if (blockIdx.x < 512) {
    int bid = blockIdx.x;
    int b = bid & 7, rt = bid >> 3;
    int n0 = rt * 64, y = rt;
    bool isq = (w < 2);
    int m0 = (w & 1) * 16;
    const us* wc = isq ? wqc : wkc;
    const us* xTb = xT + (((size_t)b << 12) * 256);
    f32x4 acc[4];
#pragma unroll
    for (int nt = 0; nt < 4; nt++) acc[nt] = (f32x4){0.f, 0.f, 0.f, 0.f};
#pragma unroll
    for (int t = 0; t < 3; t++) {
      bool killT = (!isq) && ((t == 0 && y == 0) || (t == 2 && y == 63));
      if (!killT) {
        int dn = isq ? (t - 1) : (t - 1) * 64;
#pragma unroll
        for (int k8 = 0; k8 < 8; k8++) {
          int kloc = t * 256 + k8 * 32 + quad * 8;
          bf16x8 af = *(const bf16x8*)(wc + (size_t)(m0 + l15) * 768 + kloc);
          int ic = k8 * 32 + quad * 8;
#pragma unroll
          for (int nt = 0; nt < 4; nt++) {
            int nl = nt * 16 + l15;
            int ns = n0 + nl + dn;
            ns = ns < 0 ? 0 : (ns > 4095 ? 4095 : ns);
            bf16x8 bf = *(const bf16x8*)(xTb + (size_t)ns * 256 + ic);
            if (isq && ((t == 0 && nl == 0) || (t == 2 && nl == 63)))
              bf = (bf16x8){0, 0, 0, 0, 0, 0, 0, 0};
            acc[nt] = __builtin_amdgcn_mfma_f32_16x16x32_bf16(af, bf, acc[nt], 0, 0, 0);
          }
        }
      }
    }
    const float* bias = isq ? bq : bk;
    float bsc = isq ? LOG2E : 1.0f;
    us* outp = (isq ? qT : kT) + (((size_t)b << 12) * 32);
    float b0 = bias[m0 + quad * 4 + 0] * bsc;
    float b1 = bias[m0 + quad * 4 + 1] * bsc;
    float b2 = bias[m0 + quad * 4 + 2] * bsc;
    float b3 = bias[m0 + quad * 4 + 3] * bsc;
#pragma unroll
    for (int nt = 0; nt < 4; nt++) {
      int n = n0 + nt * 16 + l15;
      unsigned lo = (unsigned)f2bf(acc[nt][0] + b0) | ((unsigned)f2bf(acc[nt][1] + b1) << 16);
      unsigned hi = (unsigned)f2bf(acc[nt][2] + b2) | ((unsigned)f2bf(acc[nt][3] + b3) << 16);
      *(uint2*)(outp + (size_t)n * 32 + m0 + quad * 4) = make_uint2(lo, hi);
    }
  } else {
    int bid = blockIdx.x - 512;
    int b = bid & 7, nt0 = bid >> 3;
    int n0 = nt0 * 64;
    const us* xTb = xT + (((size_t)b << 12) * 256);
    f32x4 acc[4][4];  // [ct][nt]
#pragma unroll
    for (int ct = 0; ct < 4; ct++)
#pragma unroll
      for (int nt = 0; nt < 4; nt++) acc[ct][nt] = (f32x4){0.f, 0.f, 0.f, 0.f};
#pragma unroll
    for (int kk = 0; kk < 8; kk++) {
      bf16x8 bfr[4];
#pragma unroll
      for (int nt = 0; nt < 4; nt++)
        bfr[nt] = *(const bf16x8*)(xTb + (size_t)(n0 + nt * 16 + l15) * 256 + kk * 32 + quad * 8);
#pragma unroll
      for (int ct = 0; ct < 4; ct++) {
        bf16x8 af = *(const bf16x8*)(wvb + (size_t)(w * 64 + ct * 16 + l15) * 256 + kk * 32 + quad * 8);
#pragma unroll
        for (int nt = 0; nt < 4; nt++)
          acc[ct][nt] = __builtin_amdgcn_mfma_f32_16x16x32_bf16(af, bfr[nt], acc[ct][nt], 0, 0, 0);
      }
    }
    us* vb = vblk + ((size_t)b << 20);
#pragma unroll
    for (int ct = 0; ct < 4; ct++) {
#pragma unroll
      for (int r = 0; r < 4; r++) {
        int oc = w * 64 + ct * 16 + quad * 4 + r;
        float bvv = bv[oc];
#pragma unroll
        for (int nt = 0; nt < 4; nt++) {
          vb[((size_t)((n0 >> 4) + nt) * 256 + oc) * 16 + l15] = f2bf(acc[ct][nt][r] + bvv);
        }
      }
    }
  }
}

// ---------------------------------------------------------------------------
// Flash attention (R3 structure verbatim) + ONE change: de-phase the two
// co-resident blocks per CU. Grid 512 round-robins 8 XCDs x 32 CUs, so the
// co-resident pair on a CU is (bid, bid+256). Both run identical-length
// steps -> phase-locked -> they hit barrier/ds_read stalls simultaneously
// and can't cross-fill (the ~1850 cy/step issue gap at 36% MfmaUtil).
// s_sleep(27) (=1728 cy ~ half step) on the second round offsets the phase
// so one block's MFMA issue lands in the other's stall windows.
// ---------------------------------------------------------------------------
__global__ __launch_bounds__(512, 4) void attn_kernel(
    const float* __restrict__ x, const us* __restrict__ qT,
    const us* __restrict__ kT, const us* __restrict__ vblk,
    const float* __restrict__ gamma_p, float* __restrict__ out) {
  __shared__ __align__(16) us pb[2][64 * 72];  // [i][j], stride 72
  __shared__ float lpart[2][64];

  int tid = threadIdx.x, lane = tid & 63, w = tid >> 6;
  int l15 = lane & 15, quad = lane >> 4;
  int l31 = lane & 31, h32 = lane >> 5;
  int tw = w & 3, jh = w >> 2;

  int bid = blockIdx.x;
  int b = bid & 7, i0 = (bid >> 3) * 64;

  const us* qTb = qT + (((size_t)b << 12) * 32);
  const us* kTb = kT + (((size_t)b << 12) * 32);
  const us* vbb = vblk + ((size_t)b << 20);

  bf16x8 qf = *(const bf16x8*)(qTb + (size_t)(i0 + tw * 16 + l15) * 32 + quad * 8);

  // De-phase: second dispatch round (co-resident partner) starts ~half-step
  // later so barrier stalls interleave with the partner's compute.
  if (bid & 256) __builtin_amdgcn_s_sleep(27);

  const us* kbase = kTb + (size_t)(jh * 32 + l15) * 32 + quad * 8;   // +jt*2048
  const us* vbase = vbb + (size_t)(w * 32 + l31) * 16 + h32 * 8;     // +jt*16384
  int pwi = (tw * 16 + l15) * 72 + jh * 32 + quad * 4;
  int pri = l31 * 72 + h32 * 8;

  float lr = 0.f;
  f32x4 s0, s1;
  f32x16 o0, o1;
#pragma unroll
  for (int rg = 0; rg < 16; rg++) { o0[rg] = 0.f; o1[rg] = 0.f; }

  bf16x8 kS0a, kS0b, kS1a, kS1b;
  bf16x8 v0_0, v0_1, v0_2, v0_3;
  bf16x8 v1_0, v1_1, v1_2, v1_3;
  bf16x8 v2_0, v2_1, v2_2, v2_3;
  bf16x8 v3_0, v3_1, v3_2, v3_3;

#define PRE(JT, KN0, KN1, VN0, VN1, VN2, VN3)                                  \
  do {                                                                         \
    int jn = (JT) & 63;                                                        \
    const us* kp = kbase + (size_t)jn * 2048;                                  \
    const us* vp = vbase + (size_t)jn * 16384;                                 \
    KN0 = *(const bf16x8*)(kp);                                                \
    KN1 = *(const bf16x8*)(kp + 512);                                          \
    VN0 = *(const bf16x8*)(vp);                                                \
    VN1 = *(const bf16x8*)(vp + 4096);                                         \
    VN2 = *(const bf16x8*)(vp + 8192);                                         \
    VN3 = *(const bf16x8*)(vp + 12288);                                        \
  } while (0)

#define QKM(KC0, KC1)                                                          \
  do {                                                                         \
    s0 = __builtin_amdgcn_mfma_f32_16x16x32_bf16(KC0, qf, (f32x4){0.f, 0.f, 0.f, 0.f}, 0, 0, 0); \
    s1 = __builtin_amdgcn_mfma_f32_16x16x32_bf16(KC1, qf, (f32x4){0.f, 0.f, 0.f, 0.f}, 0, 0, 0); \
  } while (0)

#define PVM(BUFR, VP0, VP1, VP2, VP3)                                          \
  do {                                                                         \
    const us* pr = (const us*)pb + (BUFR) * (64 * 72) + pri;                   \
    __builtin_amdgcn_s_setprio(1);                                             \
    bf16x8 pf0, pf1;                                                           \
    pf0 = *(const bf16x8*)(pr + 0);                                            \
    pf1 = *(const bf16x8*)(pr + 32 * 72 + 0);                                  \
    o0 = __builtin_amdgcn_mfma_f32_32x32x16_bf16(VP0, pf0, o0, 0, 0, 0);       \
    o1 = __builtin_amdgcn_mfma_f32_32x32x16_bf16(VP0, pf1, o1, 0, 0, 0);       \
    pf0 = *(const bf16x8*)(pr + 16);                                           \
    pf1 = *(const bf16x8*)(pr + 32 * 72 + 16);                                 \
    o0 = __builtin_amdgcn_mfma_f32_32x32x16_bf16(VP1, pf0, o0, 0, 0, 0);       \
    o1 = __builtin_amdgcn_mfma_f32_32x32x16_bf16(VP1, pf1, o1, 0, 0, 0);       \
    pf0 = *(const bf16x8*)(pr + 32);                                           \
    pf1 = *(const bf16x8*)(pr + 32 * 72 + 32);                                 \
    o0 = __builtin_amdgcn_mfma_f32_32x32x16_bf16(VP2, pf0, o0, 0, 0, 0);       \
    o1 = __builtin_amdgcn_mfma_f32_32x32x16_bf16(VP2, pf1, o1, 0, 0, 0);       \
    pf0 = *(const bf16x8*)(pr + 48);                                           \
    pf1 = *(const bf16x8*)(pr + 32 * 72 + 48);                                 \
    o0 = __builtin_amdgcn_mfma_f32_32x32x16_bf16(VP3, pf0, o0, 0, 0, 0);       \
    o1 = __builtin_amdgcn_mfma_f32_32x32x16_bf16(VP3, pf1, o1, 0, 0, 0);       \
    __builtin_amdgcn_s_setprio(0);                                             \
  } while (0)

#define SMW(BUFW)                                                              \
  do {                                                                         \
    us* pw = (us*)pb + (BUFW) * (64 * 72) + pwi;                               \
    {                                                                          \
      float p0 = __builtin_amdgcn_exp2f(s0[0]);                                \
      float p1 = __builtin_amdgcn_exp2f(s0[1]);                                \
      float p2 = __builtin_amdgcn_exp2f(s0[2]);                                \
      float p3 = __builtin_amdgcn_exp2f(s0[3]);                                \
      lr += (p0 + p1) + (p2 + p3);                                             \
      unsigned e0, e1;                                                         \
      asm("v_cvt_pk_bf16_f32 %0, %1, %2" : "=v"(e0) : "v"(p0), "v"(p1));       \
      asm("v_cvt_pk_bf16_f32 %0, %1, %2" : "=v"(e1) : "v"(p2), "v"(p3));       \
      *(uint2*)pw = make_uint2(e0, e1);                                        \
    }                                                                          \
    {                                                                          \
      float p0 = __builtin_amdgcn_exp2f(s1[0]);                                \
      float p1 = __builtin_amdgcn_exp2f(s1[1]);                                \
      float p2 = __builtin_amdgcn_exp2f(s1[2]);                                \
      float p3 = __builtin_amdgcn_exp2f(s1[3]);                                \
      lr += (p0 + p1) + (p2 + p3);                                             \
      unsigned e0, e1;                                                         \
      asm("v_cvt_pk_bf16_f32 %0, %1, %2" : "=v"(e0) : "v"(p0), "v"(p1));       \
      asm("v_cvt_pk_bf16_f32 %0, %1, %2" : "=v"(e1) : "v"(p2), "v"(p3));       \
      *(uint2*)(pw + 16) = make_uint2(e0, e1);                                 \
    }                                                                          \
  } while (0)

#define BAR                                                                    \
  do {                                                                         \
    asm volatile("s_waitcnt lgkmcnt(0)" ::: "memory");                         \
    __builtin_amdgcn_s_barrier();                                              \
    __builtin_amdgcn_sched_barrier(0);                                         \
  } while (0)

  PRE(0, kS0a, kS0b, v0_0, v0_1, v0_2, v0_3);
  PRE(1, kS1a, kS1b, v1_0, v1_1, v1_2, v1_3);
  QKM(kS0a, kS0b);
  SMW(0);
  BAR;
  PRE(2, kS0a, kS0b, v2_0, v2_1, v2_2, v2_3);
  QKM(kS1a, kS1b);
  PVM(0, v0_0, v0_1, v0_2, v0_3);
  SMW(1);
  BAR;
  PRE(3, kS1a, kS1b, v3_0, v3_1, v3_2, v3_3);
  QKM(kS0a, kS0b);
  PVM(1, v1_0, v1_1, v1_2, v1_3);
  SMW(0);
  BAR;
  PRE(4, kS0a, kS0b, v0_0, v0_1, v0_2, v0_3);
  QKM(kS1a, kS1b);
  PVM(0, v2_0, v2_1, v2_2, v2_3);
  SMW(1);
  BAR;

  for (int n4 = 1; n4 < 16; n4++) {
    int n = n4 * 4;
    PRE(n + 1, kS1a, kS1b, v1_0, v1_1, v1_2, v1_3);
    QKM(kS0a, kS0b);
    PVM(1, v3_0, v3_1, v3_2, v3_3);
    SMW(0);
    BAR;
    PRE(n + 2, kS0a, kS0b, v2_0, v2_1, v2_2, v2_3);
    QKM(kS1a, kS1b);
    PVM(0, v0_0, v0_1, v0_2, v0_3);
    SMW(1);
    BAR;
    PRE(n + 3, kS1a, kS1b, v3_0, v3_1, v3_2, v3_3);
    QKM(kS0a, kS0b);
    PVM(1, v1_0, v1_1, v1_2, v1_3);
    SMW(0);
    BAR;
    PRE(n + 4, kS0a, kS0b, v0_0, v0_1, v0_2, v0_3);
    QKM(kS1a, kS1b);
    PVM(0, v2_0, v2_1, v2_2, v2_3);
    SMW(1);
    BAR;
  }
  PVM(1, v3_0, v3_1, v3_2, v3_3);

#undef PRE
#undef QKM
#undef PVM
#undef SMW
#undef BAR

  float lt = lr;
  lt += __shfl_xor(lt, 16);
  lt += __shfl_xor(lt, 32);
  if (quad == 0) lpart[jh][tw * 16 + l15] = lt;
  __syncthreads();
  float g = gamma_p[0];
  const float* xb = x + ((size_t)b << 20);
  float* ob = out + ((size_t)b << 20);
  float gl[2];
#pragma unroll
  for (int it = 0; it < 2; it++) {
    int i = it * 32 + l31;
    gl[it] = g / (lpart[0][i] + lpart[1][i]);
  }
#pragma unroll
  for (int it = 0; it < 2; it++) {
    int i = i0 + it * 32 + l31;
    const f32x16& o = (it == 0) ? o0 : o1;
#pragma unroll
    for (int rg = 0; rg < 16; rg++) {
      int c = w * 32 + ((rg & 3) + 8 * (rg >> 2) + 4 * h32);
      size_t idx = ((size_t)c << 12) + i;
      ob[idx] = o[rg] * gl[it] + xb[idx];
    }
  }
}

// ---------------------------------------------------------------------------
extern "C" void kernel_launch(void* const* d_in, const int* in_sizes, int n_in,
                              void* d_out, int out_size, void* d_ws, size_t ws_size,
                              hipStream_t stream) {
  const float* x = (const float*)d_in[0];
  const float* wq = (const float*)d_in[1];
  const float* bq = (const float*)d_in[2];
  const float* wk = (const float*)d_in[3];
  const float* bk = (const float*)d_in[4];
  const float* wv = (const float*)d_in[5];
  const float* bv = (const float*)d_in[6];
  const float* gamma = (const float*)d_in[7];
  float* out = (float*)d_out;

  us* xT = (us*)d_ws;                 // 8,388,608
  us* qT = xT + (size_t)8388608;      // 1,048,576
  us* kT = qT + (size_t)1048576;      // 1,048,576
  us* vblk = kT + (size_t)1048576;    // 8,388,608
  us* wqc = vblk + (size_t)8388608;   // 24,576
  us* wkc = wqc + (size_t)24576;      // 24,576
  us* wvb = wkc + (size_t)24576;      // 65,536

  prep_kernel<<<2496, 256, 0, stream>>>(x, wq, wk, wv, xT, wqc, wkc, wvb);
  conv_kernel<<<1024, 256, 0, stream>>>(xT, wqc, wkc, bq, bk, wvb, bv, qT, kT, vblk);
  attn_kernel<<<512, 512, 0, stream>>>(x, qT, kT, vblk, gamma, out);
}